// Round 12
// baseline (359.638 us; speedup 1.0000x reference)
//
#include <hip/hip_runtime.h>

typedef __attribute__((ext_vector_type(8))) short short8;
typedef __attribute__((ext_vector_type(4))) float f32x4;

#define FF 256   // hidden features
#define NHEAD 4
#define HDIM 64
#define LDS_PITCH 264  // ushorts: 256 + 8 pad (528 B/row; 2-way bank alias = free)

__device__ __forceinline__ float bf2f(unsigned short u) {
  union { unsigned u; float f; } v; v.u = ((unsigned)u) << 16; return v.f;
}
__device__ __forceinline__ unsigned short f2bf(float f) {
  union { unsigned u; float f; } v; v.f = f;
  unsigned r = v.u + 0x7FFFu + ((v.u >> 16) & 1u);
  return (unsigned short)(r >> 16);
}

// A-tile 8-element fetch: bf16 passthrough or fp32->bf16 inline convert
__device__ __forceinline__ short8 loadA8(const unsigned short* p) {
  return *(const short8*)p;
}
__device__ __forceinline__ short8 loadA8(const float* p) {
  f32x4 a = *(const f32x4*)p;
  f32x4 b = *(const f32x4*)(p + 4);
  short8 r;
  r[0] = (short)f2bf(a.x); r[1] = (short)f2bf(a.y);
  r[2] = (short)f2bf(a.z); r[3] = (short)f2bf(a.w);
  r[4] = (short)f2bf(b.x); r[5] = (short)f2bf(b.y);
  r[6] = (short)f2bf(b.z); r[7] = (short)f2bf(b.w);
  return r;
}

// ------- weights fp32->bf16 (3 segments) + deg zeroing (segment 4) -------
__global__ __launch_bounds__(256) void cvtw_kernel(
    const float* __restrict__ p0, int n0, const float* __restrict__ p1, int n1,
    const float* __restrict__ p2, int n2,
    unsigned short* __restrict__ o0, unsigned short* __restrict__ o1,
    unsigned short* __restrict__ o2, int* __restrict__ deg, int nz4) {
  int i = blockIdx.x * 256 + threadIdx.x;
  const float* in;
  unsigned short* out;
  int idx;
  if (i < n0) { in = p0; out = o0; idx = i; }
  else if (i < n0 + n1) { in = p1; out = o1; idx = i - n0; }
  else if (i < n0 + n1 + n2) { in = p2; out = o2; idx = i - n0 - n1; }
  else {
    int z = i - n0 - n1 - n2;
    if (z < nz4) ((int4*)deg)[z] = int4{0, 0, 0, 0};
    return;
  }
  f32x4 v = ((const f32x4*)in)[idx];
  ushort4 o;
  o.x = f2bf(v.x); o.y = f2bf(v.y); o.z = f2bf(v.z); o.w = f2bf(v.w);
  ((ushort4*)out)[idx] = o;
}

// ---------------- CSR build ----------------
__global__ void hist_kernel(const int* __restrict__ dst, int* __restrict__ deg,
                            int E, int N) {
  int i = blockIdx.x * blockDim.x + threadIdx.x;
  if (i < E) {
    int d = dst[i];
    if ((unsigned)d < (unsigned)N) atomicAdd(&deg[d], 1);
  }
}

__global__ __launch_bounds__(256) void scan_chunks(const int* __restrict__ deg,
                                                   int* __restrict__ excl,
                                                   int* __restrict__ csum, int N) {
  __shared__ int s[256];
  int t = threadIdx.x;
  int base = blockIdx.x * 1024 + t * 4;
  int v[4];
  int sum = 0;
#pragma unroll
  for (int i = 0; i < 4; ++i) {
    v[i] = (base + i < N) ? deg[base + i] : 0;
    sum += v[i];
  }
  s[t] = sum;
  __syncthreads();
  for (int off = 1; off < 256; off <<= 1) {
    int x = (t >= off) ? s[t - off] : 0;
    __syncthreads();
    s[t] += x;
    __syncthreads();
  }
  int run = s[t] - sum;
#pragma unroll
  for (int i = 0; i < 4; ++i) {
    if (base + i < N) excl[base + i] = run;
    run += v[i];
  }
  if (t == 255) csum[blockIdx.x] = s[255];  // chunk TOTAL
}

__global__ void finalize_rows(const int* __restrict__ excl, const int* __restrict__ csum,
                              int* __restrict__ row_start, int* __restrict__ cursor,
                              int N, int E) {
  int i = blockIdx.x * blockDim.x + threadIdx.x;
  if (i < N) {
    int chunk = i >> 10;
    int pre = 0;
    for (int k = 0; k < chunk; ++k) pre += csum[k];
    int v = excl[i] + pre;
    row_start[i] = v;
    cursor[i] = v;
  }
  if (i == 0) row_start[N] = E;
}

__global__ void scatter_kernel(const int* __restrict__ src, const int* __restrict__ dst,
                               int* __restrict__ cursor, int* __restrict__ sorted_src,
                               int E, int N) {
  int i = blockIdx.x * blockDim.x + threadIdx.x;
  if (i < E) {
    int d = dst[i];
    int s = src[i];
    if ((unsigned)d < (unsigned)N) {
      int p = atomicAdd(&cursor[d], 1);
      if ((unsigned)p < (unsigned)E)
        sorted_src[p] = ((unsigned)s < (unsigned)N) ? s : 0;
    }
  }
}

// ------- main GEMM: LDS-staged A (fp32 or bf16 source) + register-resident B -------
template <typename AT>
__global__ __launch_bounds__(256) void gemm_main(const AT* __restrict__ A,
                                                 const unsigned short* __restrict__ B,
                                                 unsigned short* __restrict__ Cb,
                                                 const float* __restrict__ a_src,
                                                 const float* __restrict__ a_dst,
                                                 float* __restrict__ sS,
                                                 float* __restrict__ sD,
                                                 int M) {
  __shared__ unsigned short Atile[64 * LDS_PITCH];
  const int K = 256;
  int tid = threadIdx.x;
  int wave = tid >> 6;
  int lane = tid & 63;
  int row0w = blockIdx.x * 64;
  int col0 = wave * 64;
  int lr = lane & 15;
  int quad = lane >> 4;

  // ---- B slice into registers (same for every block; L2-hot after block 0) ----
  short8 breg[4][8];
  {
    const unsigned short* Bp0 = B + (size_t)(col0 + lr) * K + quad * 8;
#pragma unroll
    for (int t = 0; t < 4; ++t)
#pragma unroll
      for (int kk = 0; kk < 8; ++kk)
        breg[t][kk] = *(const short8*)(Bp0 + (size_t)(16 * t) * K + kk * 32);
  }

  // ---- stage A tile (64x256) once per block (fp32 path converts inline) ----
  {
#pragma unroll
    for (int pass = 0; pass < 8; ++pass) {
      int c = tid + pass * 256;
      int row = c >> 5;
      int col8 = (c & 31) * 8;
      int grow = row0w + row;
      if (grow >= M) grow = M - 1;
      short8 v = loadA8(A + (size_t)grow * K + col8);
      *(short8*)(&Atile[row * LDS_PITCH + col8]) = v;
    }
  }
  __syncthreads();

  f32x4 acc[4][4];
#pragma unroll
  for (int rt = 0; rt < 4; ++rt)
#pragma unroll
    for (int t = 0; t < 4; ++t) acc[rt][t] = f32x4{0, 0, 0, 0};

#pragma unroll
  for (int kk = 0; kk < 8; ++kk) {
    short8 a[4];
#pragma unroll
    for (int rt = 0; rt < 4; ++rt)
      a[rt] = *(const short8*)(&Atile[(rt * 16 + lr) * LDS_PITCH + quad * 8 + kk * 32]);
#pragma unroll
    for (int rt = 0; rt < 4; ++rt)
#pragma unroll
      for (int t = 0; t < 4; ++t)
        acc[rt][t] = __builtin_amdgcn_mfma_f32_16x16x32_bf16(a[rt], breg[t][kk], acc[rt][t], 0, 0, 0);
  }

#pragma unroll
  for (int rt = 0; rt < 4; ++rt) {
#pragma unroll
    for (int t = 0; t < 4; ++t) {
#pragma unroll
      for (int r = 0; r < 4; ++r) {
        int row = row0w + rt * 16 + quad * 4 + r;
        if (row < M) {
          int col = col0 + 16 * t + lr;
          Cb[(size_t)row * FF + col] = f2bf(acc[rt][t][r]);
        }
      }
    }
  }

  // fused scores: wave's 64-col span = one head
  {
    float asv[4], adv[4];
#pragma unroll
    for (int t = 0; t < 4; ++t) {
      asv[t] = a_src[col0 + 16 * t + lr];
      adv[t] = a_dst[col0 + 16 * t + lr];
    }
#pragma unroll
    for (int rt = 0; rt < 4; ++rt) {
#pragma unroll
      for (int r = 0; r < 4; ++r) {
        float ps = acc[rt][0][r] * asv[0] + acc[rt][1][r] * asv[1] +
                   acc[rt][2][r] * asv[2] + acc[rt][3][r] * asv[3];
        float pd = acc[rt][0][r] * adv[0] + acc[rt][1][r] * adv[1] +
                   acc[rt][2][r] * adv[2] + acc[rt][3][r] * adv[3];
#pragma unroll
        for (int sft = 1; sft < 16; sft <<= 1) {
          ps += __shfl_xor(ps, sft);
          pd += __shfl_xor(pd, sft);
        }
        if (lr == 0) {
          int row = row0w + rt * 16 + quad * 4 + r;
          if (row < M) {
            sS[row * NHEAD + wave] = ps;
            sD[row * NHEAD + wave] = pd;
          }
        }
      }
    }
  }
}

// ---------------- head GEMM: register-resident B, fp32 out (+bias) ----------------
__global__ __launch_bounds__(256) void gemm_head(const unsigned short* __restrict__ A,
                                                 const unsigned short* __restrict__ B,
                                                 float* __restrict__ Cf,
                                                 const float* __restrict__ bias,
                                                 int M) {
  const int K = 256;
  int wave = threadIdx.x >> 6;
  int lane = threadIdx.x & 63;
  int row0w = blockIdx.x * 256 + wave * 64;
  if (row0w >= M) return;
  int lr = lane & 15;
  int quad = lane >> 4;

  short8 breg[4][8];
  {
    const unsigned short* Bp0 = B + (size_t)lr * K + quad * 8;
#pragma unroll
    for (int t = 0; t < 4; ++t)
#pragma unroll
      for (int kk = 0; kk < 8; ++kk)
        breg[t][kk] = *(const short8*)(Bp0 + (size_t)(16 * t) * K + kk * 32);
  }

  const unsigned short* Aps[4];
#pragma unroll
  for (int rt = 0; rt < 4; ++rt) {
    int arow = row0w + rt * 16 + lr;
    if (arow >= M) arow = M - 1;
    Aps[rt] = A + (size_t)arow * K + quad * 8;
  }

  f32x4 acc[4][4];
#pragma unroll
  for (int rt = 0; rt < 4; ++rt)
#pragma unroll
    for (int t = 0; t < 4; ++t) acc[rt][t] = f32x4{0, 0, 0, 0};

#pragma unroll
  for (int kk = 0; kk < 8; ++kk) {
    short8 a[4];
#pragma unroll
    for (int rt = 0; rt < 4; ++rt) a[rt] = *(const short8*)(Aps[rt] + kk * 32);
#pragma unroll
    for (int rt = 0; rt < 4; ++rt)
#pragma unroll
      for (int t = 0; t < 4; ++t)
        acc[rt][t] = __builtin_amdgcn_mfma_f32_16x16x32_bf16(a[rt], breg[t][kk], acc[rt][t], 0, 0, 0);
  }

#pragma unroll
  for (int rt = 0; rt < 4; ++rt) {
#pragma unroll
    for (int t = 0; t < 4; ++t) {
#pragma unroll
      for (int r = 0; r < 4; ++r) {
        int row = row0w + rt * 16 + quad * 4 + r;
        if (row < M) {
          int col = 16 * t + lr;
          Cf[(size_t)row * 64 + col] = acc[rt][t][r] + bias[col];
        }
      }
    }
  }
}

// ---------------- fully-fused aggregation v3.2 ----------------
// Both 8-edge batches' loads issued back-to-back (16 gathers in flight) before FMAs.
__global__ __launch_bounds__(256) void aggregate_kernel(
    const unsigned short* __restrict__ hprev, const float* __restrict__ sS,
    const float* __restrict__ sD, const int* __restrict__ row_start,
    const int* __restrict__ sorted_src, const float* __restrict__ gamma,
    const float* __restrict__ beta, const float* __restrict__ mean,
    const float* __restrict__ var, unsigned short* __restrict__ hout, int N) {
  int wave = threadIdx.x >> 6;
  int lane = threadIdx.x & 63;
  int n = blockIdx.x * 4 + wave;
  if (n >= N) return;
  int hh = lane >> 4;
  int slot = lane & 15;
  int f0 = lane * 4;
  int srcBase = lane & 48;
  int jb = row_start[n];
  int je = row_start[n + 1];
  int jlast = je - 1;
  float sdv = sD[n * NHEAD + hh];
  float l = 0.f;
  float o0 = 0.f, o1 = 0.f, o2 = 0.f, o3 = 0.f;

  for (int c = jb; c < je; c += 16) {
    // ---- phase A: one (edge,head) per lane ----
    int j = c + slot;
    int jc = (j < jlast) ? j : jlast;
    int s = sorted_src[jc];
    float e = sS[s * NHEAD + hh] + sdv;
    e = (e >= 0.f) ? e : 0.2f * e;
    float w = (j < je) ? __expf(e) : 0.f;
    l += w;

    // ---- phase B: issue ALL loads first (up to 16 in flight), then FMAs ----
    bool b2 = (c + 8 < je);
    uint2 u[16];
#pragma unroll
    for (int k = 0; k < 8; ++k) {
      int sk = __shfl(s, srcBase + k, 64);
      u[k] = *(const uint2*)(hprev + (size_t)sk * FF + f0);
    }
    if (b2) {
#pragma unroll
      for (int k = 8; k < 16; ++k) {
        int sk = __shfl(s, srcBase + k, 64);
        u[k] = *(const uint2*)(hprev + (size_t)sk * FF + f0);
      }
    }
#pragma unroll
    for (int k = 0; k < 8; ++k) {
      float a = __shfl(w, srcBase + k, 64);
      o0 += a * __uint_as_float(u[k].x << 16);
      o1 += a * __uint_as_float(u[k].x & 0xffff0000u);
      o2 += a * __uint_as_float(u[k].y << 16);
      o3 += a * __uint_as_float(u[k].y & 0xffff0000u);
    }
    if (b2) {
#pragma unroll
      for (int k = 8; k < 16; ++k) {
        float a = __shfl(w, srcBase + k, 64);
        o0 += a * __uint_as_float(u[k].x << 16);
        o1 += a * __uint_as_float(u[k].x & 0xffff0000u);
        o2 += a * __uint_as_float(u[k].y << 16);
        o3 += a * __uint_as_float(u[k].y & 0xffff0000u);
      }
    }
  }

  l += __shfl_xor(l, 1);
  l += __shfl_xor(l, 2);
  l += __shfl_xor(l, 4);
  l += __shfl_xor(l, 8);
  float li = 1.f / fmaxf(l, 1e-9f);

  f32x4 g = *(const f32x4*)(gamma + f0);
  f32x4 b = *(const f32x4*)(beta + f0);
  f32x4 mu = *(const f32x4*)(mean + f0);
  f32x4 vr = *(const f32x4*)(var + f0);
  float v0 = (o0 * li - mu.x) * rsqrtf(vr.x + 1e-5f) * g.x + b.x;
  float v1 = (o1 * li - mu.y) * rsqrtf(vr.y + 1e-5f) * g.y + b.y;
  float v2 = (o2 * li - mu.z) * rsqrtf(vr.z + 1e-5f) * g.z + b.z;
  float v3 = (o3 * li - mu.w) * rsqrtf(vr.w + 1e-5f) * g.w + b.w;
  v0 = (v0 > 0.f) ? v0 : expm1f(v0);
  v1 = (v1 > 0.f) ? v1 : expm1f(v1);
  v2 = (v2 > 0.f) ? v2 : expm1f(v2);
  v3 = (v3 > 0.f) ? v3 : expm1f(v3);
  ushort4 ov;
  ov.x = f2bf(v0); ov.y = f2bf(v1); ov.z = f2bf(v2); ov.w = f2bf(v3);
  *(ushort4*)(hout + (size_t)n * FF + f0) = ov;
}

// ---------------- launch ----------------
extern "C" void kernel_launch(void* const* d_in, const int* in_sizes, int n_in,
                              void* d_out, int out_size, void* d_ws, size_t ws_size,
                              hipStream_t stream) {
  const float* x   = (const float*)d_in[0];
  const int* ei    = (const int*)d_in[1];
  const float* W1  = (const float*)d_in[2];
  const float* as1 = (const float*)d_in[3];
  const float* ad1 = (const float*)d_in[4];
  const float* g1  = (const float*)d_in[5];
  const float* b1  = (const float*)d_in[6];
  const float* m1  = (const float*)d_in[7];
  const float* v1  = (const float*)d_in[8];
  const float* W2  = (const float*)d_in[9];
  const float* as2 = (const float*)d_in[10];
  const float* ad2 = (const float*)d_in[11];
  const float* g2  = (const float*)d_in[12];
  const float* b2  = (const float*)d_in[13];
  const float* m2  = (const float*)d_in[14];
  const float* v2  = (const float*)d_in[15];
  const float* Wc  = (const float*)d_in[16];
  const float* bc  = (const float*)d_in[17];

  const int N = in_sizes[0] / FF;
  const int E = in_sizes[1] / 2;
  const int* srcIdx = ei;
  const int* dstIdx = ei + E;

  char* ws = (char*)d_ws;
  size_t off = 0;
  auto take = [&](size_t bytes) -> void* {
    void* p = ws + off;
    off += (bytes + 255) & ~(size_t)255;
    return p;
  };
  int* deg        = (int*)take((size_t)((N + 3) & ~3) * 4);
  int* excl       = (int*)take((size_t)N * 4);
  int* csum       = (int*)take(256 * 4);
  int* row_start  = (int*)take(((size_t)N + 1) * 4);
  int* cursor     = (int*)take((size_t)N * 4);
  int* sorted_src = (int*)take((size_t)E * 4);
  float* sS       = (float*)take((size_t)N * NHEAD * 4);
  float* sD       = (float*)take((size_t)N * NHEAD * 4);
  unsigned short* hpre = (unsigned short*)take((size_t)N * FF * 2);
  unsigned short* hact = (unsigned short*)take((size_t)N * FF * 2);
  unsigned short* w1b  = (unsigned short*)take((size_t)FF * FF * 2);
  unsigned short* w2b  = (unsigned short*)take((size_t)FF * FF * 2);
  unsigned short* wcb  = (unsigned short*)take((size_t)64 * FF * 2);

  const int tpb = 256;

  // weight conversions + deg zeroing (1 small dispatch)
  {
    int n0 = (FF * FF) / 4, n1 = (FF * FF) / 4, n2 = (64 * FF) / 4;
    int nz4 = (N + 3) / 4;
    int tot = n0 + n1 + n2 + nz4;
    cvtw_kernel<<<(tot + tpb - 1) / tpb, tpb, 0, stream>>>(W1, n0, W2, n1, Wc, n2,
                                                           w1b, w2b, wcb, deg, nz4);
  }

  // CSR build (dst-sorted edge list), reused by both layers
  hist_kernel<<<(E + tpb - 1) / tpb, tpb, 0, stream>>>(dstIdx, deg, E, N);
  int nchunks = (N + 1023) / 1024;
  scan_chunks<<<nchunks, 256, 0, stream>>>(deg, excl, csum, N);
  finalize_rows<<<(N + tpb - 1) / tpb, tpb, 0, stream>>>(excl, csum, row_start, cursor, N, E);
  scatter_kernel<<<(E + tpb - 1) / tpb, tpb, 0, stream>>>(srcIdx, dstIdx, cursor, sorted_src, E, N);

  int aggBlocks = (N + 3) / 4;
  int gemmBlocks = (N + 63) / 64;
  int headBlocks = (N + 255) / 256;

  // ---- layer 1 (A = fp32 x, converted inline during LDS staging) ----
  gemm_main<float><<<gemmBlocks, 256, 0, stream>>>(x, w1b, hpre, as1, ad1, sS, sD, N);
  aggregate_kernel<<<aggBlocks, 256, 0, stream>>>(hpre, sS, sD, row_start, sorted_src,
                                                  g1, b1, m1, v1, hact, N);
  // ---- layer 2 ----
  gemm_main<unsigned short><<<gemmBlocks, 256, 0, stream>>>(hact, w2b, hpre, as2, ad2,
                                                            sS, sD, N);
  aggregate_kernel<<<aggBlocks, 256, 0, stream>>>(hpre, sS, sD, row_start, sorted_src,
                                                  g2, b2, m2, v2, hact, N);
  // classifier head -> fp32 out (+bias)
  gemm_head<<<headBlocks, 256, 0, stream>>>(hact, wcb, (float*)d_out, bc, N);
}

// Round 13
// 335.142 us; speedup vs baseline: 1.0731x; 1.0731x over previous
//
#include <hip/hip_runtime.h>

typedef __attribute__((ext_vector_type(8))) short short8;
typedef __attribute__((ext_vector_type(4))) float f32x4;

#define FF 256   // hidden features
#define NHEAD 4
#define HDIM 64
#define LDS_PITCH 264  // ushorts: 256 + 8 pad (528 B/row; 2-way bank alias = free)

__device__ __forceinline__ float bf2f(unsigned short u) {
  union { unsigned u; float f; } v; v.u = ((unsigned)u) << 16; return v.f;
}
__device__ __forceinline__ unsigned short f2bf(float f) {
  union { unsigned u; float f; } v; v.f = f;
  unsigned r = v.u + 0x7FFFu + ((v.u >> 16) & 1u);
  return (unsigned short)(r >> 16);
}

// A-tile 8-element fetch: bf16 passthrough or fp32->bf16 inline convert
__device__ __forceinline__ short8 loadA8(const unsigned short* p) {
  return *(const short8*)p;
}
__device__ __forceinline__ short8 loadA8(const float* p) {
  f32x4 a = *(const f32x4*)p;
  f32x4 b = *(const f32x4*)(p + 4);
  short8 r;
  r[0] = (short)f2bf(a.x); r[1] = (short)f2bf(a.y);
  r[2] = (short)f2bf(a.z); r[3] = (short)f2bf(a.w);
  r[4] = (short)f2bf(b.x); r[5] = (short)f2bf(b.y);
  r[6] = (short)f2bf(b.z); r[7] = (short)f2bf(b.w);
  return r;
}

// ------- weights fp32->bf16 (3 segments) + deg zeroing (segment 4) -------
__global__ __launch_bounds__(256) void cvtw_kernel(
    const float* __restrict__ p0, int n0, const float* __restrict__ p1, int n1,
    const float* __restrict__ p2, int n2,
    unsigned short* __restrict__ o0, unsigned short* __restrict__ o1,
    unsigned short* __restrict__ o2, int* __restrict__ deg, int nz4) {
  int i = blockIdx.x * 256 + threadIdx.x;
  const float* in;
  unsigned short* out;
  int idx;
  if (i < n0) { in = p0; out = o0; idx = i; }
  else if (i < n0 + n1) { in = p1; out = o1; idx = i - n0; }
  else if (i < n0 + n1 + n2) { in = p2; out = o2; idx = i - n0 - n1; }
  else {
    int z = i - n0 - n1 - n2;
    if (z < nz4) ((int4*)deg)[z] = int4{0, 0, 0, 0};
    return;
  }
  f32x4 v = ((const f32x4*)in)[idx];
  ushort4 o;
  o.x = f2bf(v.x); o.y = f2bf(v.y); o.z = f2bf(v.z); o.w = f2bf(v.w);
  ((ushort4*)out)[idx] = o;
}

// ---------------- CSR build ----------------
__global__ void hist_kernel(const int* __restrict__ dst, int* __restrict__ deg,
                            int E, int N) {
  int i = blockIdx.x * blockDim.x + threadIdx.x;
  if (i < E) {
    int d = dst[i];
    if ((unsigned)d < (unsigned)N) atomicAdd(&deg[d], 1);
  }
}

__global__ __launch_bounds__(256) void scan_chunks(const int* __restrict__ deg,
                                                   int* __restrict__ excl,
                                                   int* __restrict__ csum, int N) {
  __shared__ int s[256];
  int t = threadIdx.x;
  int base = blockIdx.x * 1024 + t * 4;
  int v[4];
  int sum = 0;
#pragma unroll
  for (int i = 0; i < 4; ++i) {
    v[i] = (base + i < N) ? deg[base + i] : 0;
    sum += v[i];
  }
  s[t] = sum;
  __syncthreads();
  for (int off = 1; off < 256; off <<= 1) {
    int x = (t >= off) ? s[t - off] : 0;
    __syncthreads();
    s[t] += x;
    __syncthreads();
  }
  int run = s[t] - sum;
#pragma unroll
  for (int i = 0; i < 4; ++i) {
    if (base + i < N) excl[base + i] = run;
    run += v[i];
  }
  if (t == 255) csum[blockIdx.x] = s[255];  // chunk TOTAL
}

__global__ void finalize_rows(const int* __restrict__ excl, const int* __restrict__ csum,
                              int* __restrict__ row_start, int* __restrict__ cursor,
                              int N, int E) {
  int i = blockIdx.x * blockDim.x + threadIdx.x;
  if (i < N) {
    int chunk = i >> 10;
    int pre = 0;
    for (int k = 0; k < chunk; ++k) pre += csum[k];
    int v = excl[i] + pre;
    row_start[i] = v;
    cursor[i] = v;
  }
  if (i == 0) row_start[N] = E;
}

__global__ void scatter_kernel(const int* __restrict__ src, const int* __restrict__ dst,
                               int* __restrict__ cursor, int* __restrict__ sorted_src,
                               int E, int N) {
  int i = blockIdx.x * blockDim.x + threadIdx.x;
  if (i < E) {
    int d = dst[i];
    int s = src[i];
    if ((unsigned)d < (unsigned)N) {
      int p = atomicAdd(&cursor[d], 1);
      if ((unsigned)p < (unsigned)E)
        sorted_src[p] = ((unsigned)s < (unsigned)N) ? s : 0;
    }
  }
}

// ------- main GEMM: LDS-staged A (fp32 or bf16 source) + register-resident B -------
template <typename AT>
__global__ __launch_bounds__(256) void gemm_main(const AT* __restrict__ A,
                                                 const unsigned short* __restrict__ B,
                                                 unsigned short* __restrict__ Cb,
                                                 const float* __restrict__ a_src,
                                                 const float* __restrict__ a_dst,
                                                 float* __restrict__ sS,
                                                 float* __restrict__ sD,
                                                 int M) {
  __shared__ unsigned short Atile[64 * LDS_PITCH];
  const int K = 256;
  int tid = threadIdx.x;
  int wave = tid >> 6;
  int lane = tid & 63;
  int row0w = blockIdx.x * 64;
  int col0 = wave * 64;
  int lr = lane & 15;
  int quad = lane >> 4;

  // ---- B slice into registers (same for every block; L2-hot after block 0) ----
  short8 breg[4][8];
  {
    const unsigned short* Bp0 = B + (size_t)(col0 + lr) * K + quad * 8;
#pragma unroll
    for (int t = 0; t < 4; ++t)
#pragma unroll
      for (int kk = 0; kk < 8; ++kk)
        breg[t][kk] = *(const short8*)(Bp0 + (size_t)(16 * t) * K + kk * 32);
  }

  // ---- stage A tile (64x256) once per block (fp32 path converts inline) ----
  {
#pragma unroll
    for (int pass = 0; pass < 8; ++pass) {
      int c = tid + pass * 256;
      int row = c >> 5;
      int col8 = (c & 31) * 8;
      int grow = row0w + row;
      if (grow >= M) grow = M - 1;
      short8 v = loadA8(A + (size_t)grow * K + col8);
      *(short8*)(&Atile[row * LDS_PITCH + col8]) = v;
    }
  }
  __syncthreads();

  f32x4 acc[4][4];
#pragma unroll
  for (int rt = 0; rt < 4; ++rt)
#pragma unroll
    for (int t = 0; t < 4; ++t) acc[rt][t] = f32x4{0, 0, 0, 0};

#pragma unroll
  for (int kk = 0; kk < 8; ++kk) {
    short8 a[4];
#pragma unroll
    for (int rt = 0; rt < 4; ++rt)
      a[rt] = *(const short8*)(&Atile[(rt * 16 + lr) * LDS_PITCH + quad * 8 + kk * 32]);
#pragma unroll
    for (int rt = 0; rt < 4; ++rt)
#pragma unroll
      for (int t = 0; t < 4; ++t)
        acc[rt][t] = __builtin_amdgcn_mfma_f32_16x16x32_bf16(a[rt], breg[t][kk], acc[rt][t], 0, 0, 0);
  }

#pragma unroll
  for (int rt = 0; rt < 4; ++rt) {
#pragma unroll
    for (int t = 0; t < 4; ++t) {
#pragma unroll
      for (int r = 0; r < 4; ++r) {
        int row = row0w + rt * 16 + quad * 4 + r;
        if (row < M) {
          int col = col0 + 16 * t + lr;
          Cb[(size_t)row * FF + col] = f2bf(acc[rt][t][r]);
        }
      }
    }
  }

  // fused scores: wave's 64-col span = one head
  {
    float asv[4], adv[4];
#pragma unroll
    for (int t = 0; t < 4; ++t) {
      asv[t] = a_src[col0 + 16 * t + lr];
      adv[t] = a_dst[col0 + 16 * t + lr];
    }
#pragma unroll
    for (int rt = 0; rt < 4; ++rt) {
#pragma unroll
      for (int r = 0; r < 4; ++r) {
        float ps = acc[rt][0][r] * asv[0] + acc[rt][1][r] * asv[1] +
                   acc[rt][2][r] * asv[2] + acc[rt][3][r] * asv[3];
        float pd = acc[rt][0][r] * adv[0] + acc[rt][1][r] * adv[1] +
                   acc[rt][2][r] * adv[2] + acc[rt][3][r] * adv[3];
#pragma unroll
        for (int sft = 1; sft < 16; sft <<= 1) {
          ps += __shfl_xor(ps, sft);
          pd += __shfl_xor(pd, sft);
        }
        if (lr == 0) {
          int row = row0w + rt * 16 + quad * 4 + r;
          if (row < M) {
            sS[row * NHEAD + wave] = ps;
            sD[row * NHEAD + wave] = pd;
          }
        }
      }
    }
  }
}

// ---------------- head GEMM: register-resident B, fp32 out (+bias) ----------------
__global__ __launch_bounds__(256) void gemm_head(const unsigned short* __restrict__ A,
                                                 const unsigned short* __restrict__ B,
                                                 float* __restrict__ Cf,
                                                 const float* __restrict__ bias,
                                                 int M) {
  const int K = 256;
  int wave = threadIdx.x >> 6;
  int lane = threadIdx.x & 63;
  int row0w = blockIdx.x * 256 + wave * 64;
  if (row0w >= M) return;
  int lr = lane & 15;
  int quad = lane >> 4;

  short8 breg[4][8];
  {
    const unsigned short* Bp0 = B + (size_t)lr * K + quad * 8;
#pragma unroll
    for (int t = 0; t < 4; ++t)
#pragma unroll
      for (int kk = 0; kk < 8; ++kk)
        breg[t][kk] = *(const short8*)(Bp0 + (size_t)(16 * t) * K + kk * 32);
  }

  const unsigned short* Aps[4];
#pragma unroll
  for (int rt = 0; rt < 4; ++rt) {
    int arow = row0w + rt * 16 + lr;
    if (arow >= M) arow = M - 1;
    Aps[rt] = A + (size_t)arow * K + quad * 8;
  }

  f32x4 acc[4][4];
#pragma unroll
  for (int rt = 0; rt < 4; ++rt)
#pragma unroll
    for (int t = 0; t < 4; ++t) acc[rt][t] = f32x4{0, 0, 0, 0};

#pragma unroll
  for (int kk = 0; kk < 8; ++kk) {
    short8 a[4];
#pragma unroll
    for (int rt = 0; rt < 4; ++rt) a[rt] = *(const short8*)(Aps[rt] + kk * 32);
#pragma unroll
    for (int rt = 0; rt < 4; ++rt)
#pragma unroll
      for (int t = 0; t < 4; ++t)
        acc[rt][t] = __builtin_amdgcn_mfma_f32_16x16x32_bf16(a[rt], breg[t][kk], acc[rt][t], 0, 0, 0);
  }

#pragma unroll
  for (int rt = 0; rt < 4; ++rt) {
#pragma unroll
    for (int t = 0; t < 4; ++t) {
#pragma unroll
      for (int r = 0; r < 4; ++r) {
        int row = row0w + rt * 16 + quad * 4 + r;
        if (row < M) {
          int col = 16 * t + lr;
          Cf[(size_t)row * 64 + col] = acc[rt][t][r] + bias[col];
        }
      }
    }
  }
}

// ---------------- fully-fused aggregation v3.1 (R11-proven shape; VGPR 36) ----------
// Per 16-edge chunk: phase A computes w once per (edge,head); phase B runs two
// sequential 8-deep batches (loads issued together, then FMAs), u[8] reused.
// DO NOT batch to u[16]: VGPR 36->52 crosses an occupancy step (57%->36%) and
// costs +10 us (measured R12). TLP is what hides the gather latency here.
__global__ __launch_bounds__(256) void aggregate_kernel(
    const unsigned short* __restrict__ hprev, const float* __restrict__ sS,
    const float* __restrict__ sD, const int* __restrict__ row_start,
    const int* __restrict__ sorted_src, const float* __restrict__ gamma,
    const float* __restrict__ beta, const float* __restrict__ mean,
    const float* __restrict__ var, unsigned short* __restrict__ hout, int N) {
  int wave = threadIdx.x >> 6;
  int lane = threadIdx.x & 63;
  int n = blockIdx.x * 4 + wave;
  if (n >= N) return;
  int hh = lane >> 4;
  int slot = lane & 15;
  int f0 = lane * 4;
  int srcBase = lane & 48;
  int jb = row_start[n];
  int je = row_start[n + 1];
  int jlast = je - 1;
  float sdv = sD[n * NHEAD + hh];
  float l = 0.f;
  float o0 = 0.f, o1 = 0.f, o2 = 0.f, o3 = 0.f;

  for (int c = jb; c < je; c += 16) {
    int j = c + slot;
    int jc = (j < jlast) ? j : jlast;
    int s = sorted_src[jc];
    float e = sS[s * NHEAD + hh] + sdv;
    e = (e >= 0.f) ? e : 0.2f * e;
    float w = (j < je) ? __expf(e) : 0.f;
    l += w;

    {
      uint2 u[8];
#pragma unroll
      for (int k = 0; k < 8; ++k) {
        int sk = __shfl(s, srcBase + k, 64);
        u[k] = *(const uint2*)(hprev + (size_t)sk * FF + f0);
      }
#pragma unroll
      for (int k = 0; k < 8; ++k) {
        float a = __shfl(w, srcBase + k, 64);
        o0 += a * __uint_as_float(u[k].x << 16);
        o1 += a * __uint_as_float(u[k].x & 0xffff0000u);
        o2 += a * __uint_as_float(u[k].y << 16);
        o3 += a * __uint_as_float(u[k].y & 0xffff0000u);
      }
    }
    if (c + 8 < je) {
      uint2 u[8];
#pragma unroll
      for (int k = 8; k < 16; ++k) {
        int sk = __shfl(s, srcBase + k, 64);
        u[k - 8] = *(const uint2*)(hprev + (size_t)sk * FF + f0);
      }
#pragma unroll
      for (int k = 8; k < 16; ++k) {
        float a = __shfl(w, srcBase + k, 64);
        o0 += a * __uint_as_float(u[k - 8].x << 16);
        o1 += a * __uint_as_float(u[k - 8].x & 0xffff0000u);
        o2 += a * __uint_as_float(u[k - 8].y << 16);
        o3 += a * __uint_as_float(u[k - 8].y & 0xffff0000u);
      }
    }
  }

  l += __shfl_xor(l, 1);
  l += __shfl_xor(l, 2);
  l += __shfl_xor(l, 4);
  l += __shfl_xor(l, 8);
  float li = 1.f / fmaxf(l, 1e-9f);

  f32x4 g = *(const f32x4*)(gamma + f0);
  f32x4 b = *(const f32x4*)(beta + f0);
  f32x4 mu = *(const f32x4*)(mean + f0);
  f32x4 vr = *(const f32x4*)(var + f0);
  float v0 = (o0 * li - mu.x) * rsqrtf(vr.x + 1e-5f) * g.x + b.x;
  float v1 = (o1 * li - mu.y) * rsqrtf(vr.y + 1e-5f) * g.y + b.y;
  float v2 = (o2 * li - mu.z) * rsqrtf(vr.z + 1e-5f) * g.z + b.z;
  float v3 = (o3 * li - mu.w) * rsqrtf(vr.w + 1e-5f) * g.w + b.w;
  v0 = (v0 > 0.f) ? v0 : expm1f(v0);
  v1 = (v1 > 0.f) ? v1 : expm1f(v1);
  v2 = (v2 > 0.f) ? v2 : expm1f(v2);
  v3 = (v3 > 0.f) ? v3 : expm1f(v3);
  ushort4 ov;
  ov.x = f2bf(v0); ov.y = f2bf(v1); ov.z = f2bf(v2); ov.w = f2bf(v3);
  *(ushort4*)(hout + (size_t)n * FF + f0) = ov;
}

// ---------------- launch ----------------
extern "C" void kernel_launch(void* const* d_in, const int* in_sizes, int n_in,
                              void* d_out, int out_size, void* d_ws, size_t ws_size,
                              hipStream_t stream) {
  const float* x   = (const float*)d_in[0];
  const int* ei    = (const int*)d_in[1];
  const float* W1  = (const float*)d_in[2];
  const float* as1 = (const float*)d_in[3];
  const float* ad1 = (const float*)d_in[4];
  const float* g1  = (const float*)d_in[5];
  const float* b1  = (const float*)d_in[6];
  const float* m1  = (const float*)d_in[7];
  const float* v1  = (const float*)d_in[8];
  const float* W2  = (const float*)d_in[9];
  const float* as2 = (const float*)d_in[10];
  const float* ad2 = (const float*)d_in[11];
  const float* g2  = (const float*)d_in[12];
  const float* b2  = (const float*)d_in[13];
  const float* m2  = (const float*)d_in[14];
  const float* v2  = (const float*)d_in[15];
  const float* Wc  = (const float*)d_in[16];
  const float* bc  = (const float*)d_in[17];

  const int N = in_sizes[0] / FF;
  const int E = in_sizes[1] / 2;
  const int* srcIdx = ei;
  const int* dstIdx = ei + E;

  char* ws = (char*)d_ws;
  size_t off = 0;
  auto take = [&](size_t bytes) -> void* {
    void* p = ws + off;
    off += (bytes + 255) & ~(size_t)255;
    return p;
  };
  int* deg        = (int*)take((size_t)((N + 3) & ~3) * 4);
  int* excl       = (int*)take((size_t)N * 4);
  int* csum       = (int*)take(256 * 4);
  int* row_start  = (int*)take(((size_t)N + 1) * 4);
  int* cursor     = (int*)take((size_t)N * 4);
  int* sorted_src = (int*)take((size_t)E * 4);
  float* sS       = (float*)take((size_t)N * NHEAD * 4);
  float* sD       = (float*)take((size_t)N * NHEAD * 4);
  unsigned short* hpre = (unsigned short*)take((size_t)N * FF * 2);
  unsigned short* hact = (unsigned short*)take((size_t)N * FF * 2);
  unsigned short* w1b  = (unsigned short*)take((size_t)FF * FF * 2);
  unsigned short* w2b  = (unsigned short*)take((size_t)FF * FF * 2);
  unsigned short* wcb  = (unsigned short*)take((size_t)64 * FF * 2);

  const int tpb = 256;

  // weight conversions + deg zeroing (1 small dispatch)
  {
    int n0 = (FF * FF) / 4, n1 = (FF * FF) / 4, n2 = (64 * FF) / 4;
    int nz4 = (N + 3) / 4;
    int tot = n0 + n1 + n2 + nz4;
    cvtw_kernel<<<(tot + tpb - 1) / tpb, tpb, 0, stream>>>(W1, n0, W2, n1, Wc, n2,
                                                           w1b, w2b, wcb, deg, nz4);
  }

  // CSR build (dst-sorted edge list), reused by both layers
  hist_kernel<<<(E + tpb - 1) / tpb, tpb, 0, stream>>>(dstIdx, deg, E, N);
  int nchunks = (N + 1023) / 1024;
  scan_chunks<<<nchunks, 256, 0, stream>>>(deg, excl, csum, N);
  finalize_rows<<<(N + tpb - 1) / tpb, tpb, 0, stream>>>(excl, csum, row_start, cursor, N, E);
  scatter_kernel<<<(E + tpb - 1) / tpb, tpb, 0, stream>>>(srcIdx, dstIdx, cursor, sorted_src, E, N);

  int aggBlocks = (N + 3) / 4;
  int gemmBlocks = (N + 63) / 64;
  int headBlocks = (N + 255) / 256;

  // ---- layer 1 (A = fp32 x, converted inline during LDS staging) ----
  gemm_main<float><<<gemmBlocks, 256, 0, stream>>>(x, w1b, hpre, as1, ad1, sS, sD, N);
  aggregate_kernel<<<aggBlocks, 256, 0, stream>>>(hpre, sS, sD, row_start, sorted_src,
                                                  g1, b1, m1, v1, hact, N);
  // ---- layer 2 ----
  gemm_main<unsigned short><<<gemmBlocks, 256, 0, stream>>>(hact, w2b, hpre, as2, ad2,
                                                            sS, sD, N);
  aggregate_kernel<<<aggBlocks, 256, 0, stream>>>(hpre, sS, sD, row_start, sorted_src,
                                                  g2, b2, m2, v2, hact, N);
  // classifier head -> fp32 out (+bias)
  gemm_head<<<headBlocks, 256, 0, stream>>>(hact, wcb, (float*)d_out, bc, N);
}